// Round 1
// baseline (415.030 us; speedup 1.0000x reference)
//
#include <hip/hip_runtime.h>

// LightGCN on MI355X, round 19.
// r1..r13: gather CSR + bf16 tables + quad-edge dual-row gather -> 419.
// r14: concurrent builds -> 410. r15: FAILED (cap sized at wrong granularity).
// r16: 407. r17: sub-cursors -> 410 (no gain). r18: sequential-write build
//      (pass_a LDS bin + block-contiguous flush, pass_b bucket gather/sort)
//      -> 392.7. Top-5 dispatches now all spmm_bf16 @ ~60 us (3x = 180 us,
//      46% of total). VALUBusy 54%, Mfma 0, FETCH 159 MB, hbm 39% - neither
//      pipe saturated => stall-bound.
// r19: spmm gather-MLP redesign. Old inner loop consumed each step's 2 uint2
//      gathers immediately -> next step's gathers issue only after vmcnt
//      drain => ~2 loads in flight/wave, ~8 serialized ~300cy hops per chunk
//      (matches ~2950 cy/wave observed vs ~600 cy of issue work). New loop:
//      8-lane groups x dwordx4 (16B/lane, same 128B/edge coalescing, half the
//      VMEM+shfl per edge); per 4-step PHASE all 8 p-words extracted then all
//      8 gathers issued BEFORE any fma -> MLP 2->8. Padded steps gather row 0
//      with val=+0.0 (exact, L1-hot). Predict spmm 60 -> 32-42 us,
//      VALUBusy -> 70-85%, FETCH/WRITE unchanged.

#define MM 100000
#define UU 50000
#define DD 64
#define RPB 128           // rows per bucket
#define BSH 7
#define NBMAX 800
#define CHUNK 4096
#define STAGE_B 4608      // pass_b stage entries (= CAPE_II)
#define CAPE_II 4608      // edges stride II
#define CAPE_UI 1024      // edges stride UI

__device__ __forceinline__ unsigned short f2bf(float f) {
    unsigned int b = __float_as_uint(f);
    b += 0x7FFF + ((b >> 16) & 1);          // round-to-nearest-even
    return (unsigned short)(b >> 16);
}
// packed edge: (dst << 15) | (bf16(val) & 0x7FFF); val >= 0 so sign bit unused
__device__ __forceinline__ float pk_val(unsigned int w) {
    return __uint_as_float((w & 0x7FFFu) << 16);
}
__device__ __forceinline__ int pk_dst(unsigned int w) { return (int)(w >> 15); }

// ---- pass A: LDS binning, block-contiguous sequential flush + offset table ----
// tmp entry: dst | (src & 127) << 17 ; tab row c: exclusive bucket offsets [nb+1]
__global__ void pass_a(const int* __restrict__ src_ii, const int* __restrict__ dst_ii,
                       const float* __restrict__ val_ii, int2* __restrict__ tmp_ii,
                       int* __restrict__ tab_ii, int nnz_ii, int nb_ii, int nchunks_ii,
                       const int* __restrict__ src_ui, const int* __restrict__ dst_ui,
                       const float* __restrict__ val_ui, int2* __restrict__ tmp_ui,
                       int* __restrict__ tab_ui, int nnz_ui, int nb_ui,
                       const unsigned char* __restrict__ filter) {
    extern __shared__ char smem[];
    int2* stage = (int2*)smem;                     // CHUNK entries (32 KB)
    int*  lcnt  = (int*)(smem + CHUNK * 8);        // NBMAX
    int*  lbase = lcnt + NBMAX;                    // NBMAX+1
    int*  lcur  = lbase + NBMAX + 1;               // NBMAX
    const bool is_ii = (blockIdx.x < (unsigned)nchunks_ii);
    const int chunk_id = is_ii ? blockIdx.x : (blockIdx.x - nchunks_ii);
    const int* __restrict__ src = is_ii ? src_ii : src_ui;
    const int* __restrict__ dst = is_ii ? dst_ii : dst_ui;
    const float* __restrict__ val = is_ii ? val_ii : val_ui;
    int2* __restrict__ tmp = is_ii ? tmp_ii : tmp_ui;
    int*  __restrict__ tab = is_ii ? tab_ii : tab_ui;
    const int nnz = is_ii ? nnz_ii : nnz_ui;
    const int nb  = is_ii ? nb_ii : nb_ui;
    const unsigned char* __restrict__ flt = is_ii ? nullptr : filter;

    int t = threadIdx.x;
    for (int i = t; i < nb; i += blockDim.x) lcnt[i] = 0;
    __syncthreads();
    int beg = chunk_id * CHUNK, end = min(nnz, beg + CHUNK);
    for (int i = beg + t; i < end; i += blockDim.x) {
        int s = src[i];
        if (flt && !flt[s]) continue;
        atomicAdd(&lcnt[s >> BSH], 1);
    }
    __syncthreads();
    // wave 0: exclusive scan lcnt -> lbase[0..nb], lbase[nb] = total
    if (t < 64) {
        int carry = 0;
        for (int g = 0; g < nb; g += 64) {
            int i = g + t;
            int v = (i < nb) ? lcnt[i] : 0;
            int incl = v;
            #pragma unroll
            for (int m = 1; m < 64; m <<= 1) {
                int u = __shfl_up(incl, m, 64);
                if (t >= m) incl += u;
            }
            if (i < nb) lbase[i] = carry + incl - v;
            carry += __shfl(incl, 63, 64);
        }
        if (t == 0) lbase[nb] = carry;
    }
    __syncthreads();
    for (int i = t; i < nb; i += blockDim.x) lcur[i] = lbase[i];
    __syncthreads();
    // bin into LDS stage
    for (int i = beg + t; i < end; i += blockDim.x) {
        int s = src[i];
        if (flt && !flt[s]) continue;
        int b = s >> BSH;
        int pos = atomicAdd(&lcur[b], 1);
        stage[pos] = make_int2(dst[i] | ((s & (RPB - 1)) << 17), __float_as_int(val[i]));
    }
    __syncthreads();
    // SEQUENTIAL flush: block-contiguous region + table row
    int total = lbase[nb];
    int2* outp = tmp + (size_t)chunk_id * CHUNK;
    for (int i = t; i < total; i += blockDim.x) outp[i] = stage[i];
    int* trow = tab + (size_t)chunk_id * (nb + 1);
    for (int i = t; i <= nb; i += blockDim.x) trow[i] = lbase[i];
}

// ---- pass B: block = bucket; gather segments via table, LDS sort, sequential write ----
__global__ void pass_b(const int2* __restrict__ tmp_ii, const int* __restrict__ tab_ii,
                       int nch_ii, unsigned int* __restrict__ edges_ii,
                       int* __restrict__ rp_ii, int* __restrict__ rpe_ii, int nb_ii,
                       const int2* __restrict__ tmp_ui, const int* __restrict__ tab_ui,
                       int nch_ui, unsigned int* __restrict__ edges_ui,
                       int* __restrict__ rp_ui, int* __restrict__ rpe_ui) {
    __shared__ int2 stage[STAGE_B];            // 36,864 B
    __shared__ unsigned int outs[STAGE_B];     // 18,432 B
    __shared__ int tsum[512];
    __shared__ int cnt[RPB];
    __shared__ int cur[RPB];
    __shared__ int sc[RPB];
    const bool is_ii = (blockIdx.x < (unsigned)nb_ii);
    const int b = is_ii ? blockIdx.x : (blockIdx.x - nb_ii);
    const int2* __restrict__ tmp = is_ii ? tmp_ii : tmp_ui;
    const int* __restrict__ tab = is_ii ? tab_ii : tab_ui;
    unsigned int* __restrict__ edges = is_ii ? edges_ii : edges_ui;
    int* __restrict__ rp  = is_ii ? rp_ii : rp_ui;
    int* __restrict__ rpe = is_ii ? rpe_ii : rpe_ui;
    const int nch = is_ii ? nch_ii : nch_ui;
    const int nbp1 = (is_ii ? nb_ii : (gridDim.x - nb_ii)) + 1;
    const int n_rows = is_ii ? MM : UU;
    const int cap_e = is_ii ? CAPE_II : CAPE_UI;

    int t = threadIdx.x;
    // phase 0: per-thread segment-length sums over assigned chunks
    int mysum = 0;
    for (int c = t; c < nch; c += 512)
        mysum += tab[(size_t)c * nbp1 + b + 1] - tab[(size_t)c * nbp1 + b];
    tsum[t] = mysum;
    __syncthreads();
    for (int off = 1; off < 512; off <<= 1) {
        int u = (t >= off) ? tsum[t - off] : 0;
        __syncthreads();
        tsum[t] += u;
        __syncthreads();
    }
    int mybase = tsum[t] - mysum;
    int total = tsum[511];
    // phase 1: gather segments into LDS stage (random ~84B reads, high MLP)
    for (int c = t; c < nch; c += 512) {
        int s0 = tab[(size_t)c * nbp1 + b];
        int s1 = tab[(size_t)c * nbp1 + b + 1];
        const int2* seg = tmp + (size_t)c * CHUNK + s0;
        for (int k = 0; k < s1 - s0; k++) stage[mybase++] = seg[k];
    }
    __syncthreads();
    // phase 2: row hist -> scan -> rp/rpe -> scatter to LDS out -> sequential store
    if (t < RPB) cnt[t] = 0;
    __syncthreads();
    for (int i = t; i < total; i += 512)
        atomicAdd(&cnt[(stage[i].x >> 17) & (RPB - 1)], 1);
    __syncthreads();
    int v = 0;
    if (t < RPB) { v = cnt[t]; sc[t] = v; }
    __syncthreads();
    for (int off = 1; off < RPB; off <<= 1) {
        int u = 0;
        if (t < RPB && t >= off) u = sc[t - off];
        __syncthreads();
        if (t < RPB) sc[t] += u;
        __syncthreads();
    }
    int ebeg = b * cap_e;
    if (t < RPB) {
        int excl = sc[t] - v;
        int r = (b << BSH) + t;
        if (r < n_rows) { rp[r] = ebeg + excl; rpe[r] = ebeg + excl + v; }
        cur[t] = excl;
    }
    __syncthreads();
    for (int i = t; i < total; i += 512) {
        int2 e = stage[i];
        int s = (e.x >> 17) & (RPB - 1);
        int pos = atomicAdd(&cur[s], 1);
        outs[pos] = ((unsigned int)(e.x & 0x1FFFF) << 15) | (f2bf(__int_as_float(e.y)) & 0x7FFFu);
    }
    __syncthreads();
    unsigned int* eg = edges + (size_t)ebeg;
    for (int i = t; i < total; i += 512) eg[i] = outs[i];
}

// ---- fp32 -> bf16 table conversion ----
__global__ void conv_bf16(const float4* __restrict__ in, ushort4* __restrict__ out, int n4) {
    int i = blockIdx.x * blockDim.x + threadIdx.x;
    if (i >= n4) return;
    float4 v = in[i];
    ushort4 o;
    o.x = f2bf(v.x); o.y = f2bf(v.y); o.z = f2bf(v.z); o.w = f2bf(v.w);
    out[i] = o;
}

// 8 fma: one dwordx4 of bf16 row data (8 elems) scaled by v into acc[0..7]
#define FMA8(acc, u, v) \
    acc[0] = fmaf(v, __uint_as_float((u).x << 16), acc[0]); \
    acc[1] = fmaf(v, __uint_as_float((u).x & 0xFFFF0000u), acc[1]); \
    acc[2] = fmaf(v, __uint_as_float((u).y << 16), acc[2]); \
    acc[3] = fmaf(v, __uint_as_float((u).y & 0xFFFF0000u), acc[3]); \
    acc[4] = fmaf(v, __uint_as_float((u).z << 16), acc[4]); \
    acc[5] = fmaf(v, __uint_as_float((u).z & 0xFFFF0000u), acc[5]); \
    acc[6] = fmaf(v, __uint_as_float((u).w << 16), acc[6]); \
    acc[7] = fmaf(v, __uint_as_float((u).w & 0xFFFF0000u), acc[7])

// One 4-step phase: extract all 8 p-words, issue all 8 gathers, THEN consume.
// Padded steps (st >= stepsX) use p=0 -> gather row 0 (L1-hot) with val=+0.0.
#define SPMM_PHASE(BASE) do { \
    unsigned int pa0 = ((BASE)+0 < stepsA) ? (unsigned)__shfl((int)evA, g + ((BASE)+0)*8, 64) : 0u; \
    unsigned int pa1 = ((BASE)+1 < stepsA) ? (unsigned)__shfl((int)evA, g + ((BASE)+1)*8, 64) : 0u; \
    unsigned int pa2 = ((BASE)+2 < stepsA) ? (unsigned)__shfl((int)evA, g + ((BASE)+2)*8, 64) : 0u; \
    unsigned int pa3 = ((BASE)+3 < stepsA) ? (unsigned)__shfl((int)evA, g + ((BASE)+3)*8, 64) : 0u; \
    unsigned int pb0 = ((BASE)+0 < stepsB) ? (unsigned)__shfl((int)evB, g + ((BASE)+0)*8, 64) : 0u; \
    unsigned int pb1 = ((BASE)+1 < stepsB) ? (unsigned)__shfl((int)evB, g + ((BASE)+1)*8, 64) : 0u; \
    unsigned int pb2 = ((BASE)+2 < stepsB) ? (unsigned)__shfl((int)evB, g + ((BASE)+2)*8, 64) : 0u; \
    unsigned int pb3 = ((BASE)+3 < stepsB) ? (unsigned)__shfl((int)evB, g + ((BASE)+3)*8, 64) : 0u; \
    const uint4 A0 = *(const uint4*)(xbl + ((size_t)(pa0 >> 15) << 7)); \
    const uint4 A1 = *(const uint4*)(xbl + ((size_t)(pa1 >> 15) << 7)); \
    const uint4 A2 = *(const uint4*)(xbl + ((size_t)(pa2 >> 15) << 7)); \
    const uint4 A3 = *(const uint4*)(xbl + ((size_t)(pa3 >> 15) << 7)); \
    const uint4 B0 = *(const uint4*)(xbl + ((size_t)(pb0 >> 15) << 7)); \
    const uint4 B1 = *(const uint4*)(xbl + ((size_t)(pb1 >> 15) << 7)); \
    const uint4 B2 = *(const uint4*)(xbl + ((size_t)(pb2 >> 15) << 7)); \
    const uint4 B3 = *(const uint4*)(xbl + ((size_t)(pb3 >> 15) << 7)); \
    float va0 = pk_val(pa0), va1 = pk_val(pa1), va2 = pk_val(pa2), va3 = pk_val(pa3); \
    float vb0 = pk_val(pb0), vb1 = pk_val(pb1), vb2 = pk_val(pb2), vb3 = pk_val(pb3); \
    FMA8(a, A0, va0); FMA8(a, A1, va1); FMA8(a, A2, va2); FMA8(a, A3, va3); \
    FMA8(b, B0, vb0); FMA8(b, B1, vb1); FMA8(b, B2, vb2); FMA8(b, B3, vb3); \
} while (0)

// ---- propagation SpMM: dual-row, 8-lane x dwordx4 gather, phase-prefetched ----
template <bool WRITE_Y, bool INIT_ACC>
__global__ void spmm_bf16(const int* __restrict__ rp, const int* __restrict__ rpe,
                          const unsigned int* __restrict__ edges,
                          const unsigned short* __restrict__ xb, unsigned short* __restrict__ yb,
                          const unsigned short* __restrict__ e0b, unsigned short* __restrict__ accb,
                          const float* __restrict__ att, int layer, int n_rows) {
    int wid = (blockIdx.x * blockDim.x + threadIdx.x) >> 6;
    int lane = threadIdx.x & 63;
    int r0 = wid * 2;
    if (r0 >= n_rows) return;
    int r1 = r0 + 1;
    bool has1 = (r1 < n_rows);
    int g = lane >> 3;                       // edge slot within step (8 edges/step)
    int sub = lane & 7;                      // 16B sub-position within 128B row
    const char* xbl = (const char*)xb + sub * 16;
    int eA = rp[r0], endA = rpe[r0];
    int eB = has1 ? rp[r1] : 0, endB = has1 ? rpe[r1] : 0;
    float a[8], b[8];
    #pragma unroll
    for (int k = 0; k < 8; ++k) { a[k] = 0.f; b[k] = 0.f; }
    while (eA < endA || eB < endB) {
        unsigned int evA = 0u, evB = 0u;
        int stepsA = 0, stepsB = 0;
        if (eA < endA) {
            int idx = eA + lane;
            evA = (idx < endA) ? edges[idx] : 0u;
            stepsA = (min(64, endA - eA) + 7) >> 3;
        }
        if (eB < endB) {
            int idx = eB + lane;
            evB = (idx < endB) ? edges[idx] : 0u;
            stepsB = (min(64, endB - eB) + 7) >> 3;
        }
        int steps = max(stepsA, stepsB);
        SPMM_PHASE(0);
        if (steps > 4) SPMM_PHASE(4);
        eA += 64; eB += 64;
    }
    // reduce across the 8 groups (lanes differing in bits 3..5)
    #pragma unroll
    for (int k = 0; k < 8; ++k) {
        a[k] += __shfl_xor(a[k], 8, 64);
        a[k] += __shfl_xor(a[k], 16, 64);
        a[k] += __shfl_xor(a[k], 32, 64);
        b[k] += __shfl_xor(b[k], 8, 64);
        b[k] += __shfl_xor(b[k], 16, 64);
        b[k] += __shfl_xor(b[k], 32, 64);
    }
    if (lane < 16 && (lane < 8 || has1)) {
        float s[8];
        #pragma unroll
        for (int k = 0; k < 8; ++k) s[k] = (lane < 8) ? a[k] : b[k];
        int r = (lane < 8) ? r0 : r1;
        float aa = att[layer];
        #pragma unroll
        for (int k = 0; k < 8; ++k) s[k] *= aa;
        size_t o = (size_t)r * DD + (size_t)(lane & 7) * 8;   // ushort units, 16B aligned
        if (WRITE_Y) {
            uint4 pk;
            pk.x = (unsigned)f2bf(s[0]) | ((unsigned)f2bf(s[1]) << 16);
            pk.y = (unsigned)f2bf(s[2]) | ((unsigned)f2bf(s[3]) << 16);
            pk.z = (unsigned)f2bf(s[4]) | ((unsigned)f2bf(s[5]) << 16);
            pk.w = (unsigned)f2bf(s[6]) | ((unsigned)f2bf(s[7]) << 16);
            *(uint4*)(yb + o) = pk;
        }
        const uint4 u0 = *(const uint4*)((INIT_ACC ? e0b : accb) + o);
        s[0] += __uint_as_float(u0.x << 16);
        s[1] += __uint_as_float(u0.x & 0xFFFF0000u);
        s[2] += __uint_as_float(u0.y << 16);
        s[3] += __uint_as_float(u0.y & 0xFFFF0000u);
        s[4] += __uint_as_float(u0.z << 16);
        s[5] += __uint_as_float(u0.z & 0xFFFF0000u);
        s[6] += __uint_as_float(u0.w << 16);
        s[7] += __uint_as_float(u0.w & 0xFFFF0000u);
        uint4 pk2;
        pk2.x = (unsigned)f2bf(s[0]) | ((unsigned)f2bf(s[1]) << 16);
        pk2.y = (unsigned)f2bf(s[2]) | ((unsigned)f2bf(s[3]) << 16);
        pk2.z = (unsigned)f2bf(s[4]) | ((unsigned)f2bf(s[5]) << 16);
        pk2.w = (unsigned)f2bf(s[6]) | ((unsigned)f2bf(s[7]) << 16);
        *(uint4*)(accb + o) = pk2;
    }
}

__global__ void set_bitmap(const int* __restrict__ users, unsigned char* __restrict__ bm, int B) {
    int i = blockIdx.x * blockDim.x + threadIdx.x;
    if (i < B) bm[users[i]] = 1;
}

// fused UI-SpMM + pair dot: quad-edge gather over bf16 acc table (frozen)
__global__ void user_dot_kernel(const int* __restrict__ users, const int* __restrict__ items,
                                const int* __restrict__ rp, const int* __restrict__ rpe,
                                const unsigned int* __restrict__ edges,
                                const unsigned short* __restrict__ accb,
                                float* __restrict__ out, int B) {
    int w = (blockIdx.x * blockDim.x + threadIdx.x) >> 6;
    int lane = threadIdx.x & 63;
    if (w >= B) return;
    int q = lane >> 4, sub = lane & 15;
    int u = users[w];
    int beg = rp[u], end = rpe[u];
    float s0 = 0.f, s1 = 0.f, s2 = 0.f, s3 = 0.f;
    for (int e = beg; e < end; e += 64) {
        int idx = e + lane;
        unsigned int ev = (idx < end) ? edges[idx] : 0u;
        int cnt = min(64, end - e);
        int steps = (cnt + 3) >> 2;
        int jq = q;
        for (int st = 0; st < steps; ++st, jq += 4) {
            unsigned int p = (unsigned)__shfl((int)ev, jq, 64);
            float v = pk_val(p);
            const uint2 x = *((const uint2*)(accb + ((size_t)pk_dst(p) << 6)) + sub);
            s0 = fmaf(v, __uint_as_float(x.x << 16), s0);
            s1 = fmaf(v, __uint_as_float(x.x & 0xFFFF0000u), s1);
            s2 = fmaf(v, __uint_as_float(x.y << 16), s2);
            s3 = fmaf(v, __uint_as_float(x.y & 0xFFFF0000u), s3);
        }
    }
    s0 += __shfl_xor(s0, 16, 64); s0 += __shfl_xor(s0, 32, 64);
    s1 += __shfl_xor(s1, 16, 64); s1 += __shfl_xor(s1, 32, 64);
    s2 += __shfl_xor(s2, 16, 64); s2 += __shfl_xor(s2, 32, 64);
    s3 += __shfl_xor(s3, 16, 64); s3 += __shfl_xor(s3, 32, 64);
    float p = 0.f;
    if (lane < 16) {
        const uint2 iu = *((const uint2*)(accb + ((size_t)items[w] << 6)) + sub);
        p = s0 * __uint_as_float(iu.x << 16)
          + s1 * __uint_as_float(iu.x & 0xFFFF0000u)
          + s2 * __uint_as_float(iu.y << 16)
          + s3 * __uint_as_float(iu.y & 0xFFFF0000u);
        #pragma unroll
        for (int m = 8; m >= 1; m >>= 1) p += __shfl_xor(p, m, 64);
        if (sub == 0) out[w] = p * 0.0625f;   // (1/4 mean) each side
    }
}

extern "C" void kernel_launch(void* const* d_in, const int* in_sizes, int n_in,
                              void* d_out, int out_size, void* d_ws, size_t ws_size,
                              hipStream_t stream) {
    const int*   users    = (const int*)d_in[0];
    const int*   items    = (const int*)d_in[1];
    const int*   ii_src   = (const int*)d_in[2];
    const int*   ii_dst   = (const int*)d_in[3];
    const float* ii_val   = (const float*)d_in[4];
    const int*   ui_src   = (const int*)d_in[5];
    const int*   ui_dst   = (const int*)d_in[6];
    const float* ui_val   = (const float*)d_in[7];
    const float* item_emb = (const float*)d_in[8];
    const float* att      = (const float*)d_in[9];

    const int E_ii = in_sizes[2];
    const int E_ui = in_sizes[5];
    const int B    = in_sizes[0];
    const int NB_ii = (MM + RPB - 1) / RPB;              // 782
    const int NB_ui = (UU + RPB - 1) / RPB;              // 391
    const int nchunks_ii = (E_ii + CHUNK - 1) / CHUNK;   // 782
    const int nchunks_ui = (E_ui + CHUNK - 1) / CHUNK;   // 391

    char* w = (char*)d_ws;
    // tmp_ii 782*4096*8 = 25,624,576; overlaid after pass_b by xb0+y1 (25.6 MB)
    int2*  tmp_ii = (int2*)(w);
    unsigned short* xb0 = (unsigned short*)(w);                   // 12.8 MB
    unsigned short* y1  = (unsigned short*)(w + 12800000);        // 12.8 MB
    // tmp_ui 391*4096*8 = 12,812,288 @25,624,576; overlaid by y2 (12.8 MB)
    int2*  tmp_ui = (int2*)(w + 25624576);
    unsigned short* y2  = (unsigned short*)(w + 25624576);
    unsigned short* accb = (unsigned short*)(w + 38436864);       // 12.8 MB bf16
    unsigned int* edges_ii = (unsigned int*)(w + 51236864);       // 782*4608*4 = 14,413,824
    unsigned int* edges_ui = (unsigned int*)(w + 65650688);       // 391*1024*4 = 1,601,536
    int*   tab_ii = (int*)(w + 67252224);                         // 782*783*4 = 2,449,224
    int*   tab_ui = (int*)(w + 69701448);                         // 391*392*4 = 613,088
    int*   rp_ii  = (int*)(w + 70314536);                         // (MM+2)*4
    int*   rpe_ii = (int*)(w + 70714544);
    int*   rp_ui  = (int*)(w + 71114552);                         // (UU+2)*4
    int*   rpe_ui = (int*)(w + 71314560);
    unsigned char* bitmap = (unsigned char*)(w + 71514568);       // UU bytes

    const int TB = 256;
    const int TBB = 512;
    const size_t smem_a = CHUNK * 8 + (3 * NBMAX + 8) * 4;   // ~42.4 KB -> 3 blocks/CU

    // ---- bitmap memset + set ----
    hipMemsetAsync(bitmap, 0, UU, stream);
    set_bitmap<<<(B + TB - 1) / TB, TB, 0, stream>>>(users, bitmap, B);

    // ---- both graphs: binning (sequential flush) + bucket gather/sort ----
    pass_a<<<nchunks_ii + nchunks_ui, TBB, smem_a, stream>>>(
        ii_src, ii_dst, ii_val, tmp_ii, tab_ii, E_ii, NB_ii, nchunks_ii,
        ui_src, ui_dst, ui_val, tmp_ui, tab_ui, E_ui, NB_ui, bitmap);
    pass_b<<<NB_ii + NB_ui, TBB, 0, stream>>>(
        tmp_ii, tab_ii, nchunks_ii, edges_ii, rp_ii, rpe_ii, NB_ii,
        tmp_ui, tab_ui, nchunks_ui, edges_ui, rp_ui, rpe_ui);

    // ---- bf16 x0 (overlays tmp_ii - dead after pass_b), 3 layers ----
    const int n4 = MM * DD / 4;
    conv_bf16<<<(n4 + TB - 1) / TB, TB, 0, stream>>>((const float4*)item_emb, (ushort4*)xb0, n4);
    const int nwaves = (MM + 1) / 2;                      // dual-row waves
    const int ii_blocks = (nwaves * 64 + TB - 1) / TB;
    spmm_bf16<true,  true ><<<ii_blocks, TB, 0, stream>>>(rp_ii, rpe_ii, edges_ii, xb0, y1, xb0, accb, att, 0, MM);
    spmm_bf16<true,  false><<<ii_blocks, TB, 0, stream>>>(rp_ii, rpe_ii, edges_ii, y1,  y2, nullptr, accb, att, 1, MM);
    spmm_bf16<false, false><<<ii_blocks, TB, 0, stream>>>(rp_ii, rpe_ii, edges_ii, y2,  nullptr, nullptr, accb, att, 2, MM);

    // ---- fused user aggregation + pair dot ----
    user_dot_kernel<<<(B * 64 + TB - 1) / TB, TB, 0, stream>>>(users, items, rp_ui, rpe_ui, edges_ui, accb,
                                                               (float*)d_out, B);
}

// Round 2
// 395.634 us; speedup vs baseline: 1.0490x; 1.0490x over previous
//
#include <hip/hip_runtime.h>

// LightGCN on MI355X, round 20.
// r1..r13: gather CSR + bf16 tables + quad-edge dual-row gather -> 419.
// r14: concurrent builds -> 410. r16: 407. r18: sequential-write build -> 392.7
//      (spmm 3x60us, VALUBusy 54%, stall-bound, MLP ~2).
// r19: FAILED (415). 8-deep gather batch went in (VGPR 20->52 proves loads
//      hoisted) but fixed 4-step phases quantized FMA work at 32-edge/row-pair
//      granularity: E[phases]=1.7 -> ~109 lane-FMA/chunk vs ~74 needed (+45%
//      pad-FMA waste; fmaf(0,..) still costs a VALU slot). VALU busy-TIME
//      32.6 -> 37.5us. MLP won, padding lost.
// r20: keep the 8-deep gather batch, delete the dead FMAs. stepsA/stepsB are
//      wave-uniform -> guard each FMA8 block with a scalar branch (s_cbranch,
//      ~2 SALU per skip vs 8 VALU saved); gathers stay unconditional (pad
//      gathers hit row 0, L1-hot, no VALU). Bit-identical numerics.
//      Diagnostic: VGPR ~52 = loads still hoisted (good); ~28 = compiler sank
//      them into the guards (fallback ~= r18). Predict spmm 69 -> 42-52us,
//      VALUBusy 60-75%, FETCH/WRITE unchanged.

#define MM 100000
#define UU 50000
#define DD 64
#define RPB 128           // rows per bucket
#define BSH 7
#define NBMAX 800
#define CHUNK 4096
#define STAGE_B 4608      // pass_b stage entries (= CAPE_II)
#define CAPE_II 4608      // edges stride II
#define CAPE_UI 1024      // edges stride UI

__device__ __forceinline__ unsigned short f2bf(float f) {
    unsigned int b = __float_as_uint(f);
    b += 0x7FFF + ((b >> 16) & 1);          // round-to-nearest-even
    return (unsigned short)(b >> 16);
}
// packed edge: (dst << 15) | (bf16(val) & 0x7FFF); val >= 0 so sign bit unused
__device__ __forceinline__ float pk_val(unsigned int w) {
    return __uint_as_float((w & 0x7FFFu) << 16);
}
__device__ __forceinline__ int pk_dst(unsigned int w) { return (int)(w >> 15); }

// ---- pass A: LDS binning, block-contiguous sequential flush + offset table ----
// tmp entry: dst | (src & 127) << 17 ; tab row c: exclusive bucket offsets [nb+1]
__global__ void pass_a(const int* __restrict__ src_ii, const int* __restrict__ dst_ii,
                       const float* __restrict__ val_ii, int2* __restrict__ tmp_ii,
                       int* __restrict__ tab_ii, int nnz_ii, int nb_ii, int nchunks_ii,
                       const int* __restrict__ src_ui, const int* __restrict__ dst_ui,
                       const float* __restrict__ val_ui, int2* __restrict__ tmp_ui,
                       int* __restrict__ tab_ui, int nnz_ui, int nb_ui,
                       const unsigned char* __restrict__ filter) {
    extern __shared__ char smem[];
    int2* stage = (int2*)smem;                     // CHUNK entries (32 KB)
    int*  lcnt  = (int*)(smem + CHUNK * 8);        // NBMAX
    int*  lbase = lcnt + NBMAX;                    // NBMAX+1
    int*  lcur  = lbase + NBMAX + 1;               // NBMAX
    const bool is_ii = (blockIdx.x < (unsigned)nchunks_ii);
    const int chunk_id = is_ii ? blockIdx.x : (blockIdx.x - nchunks_ii);
    const int* __restrict__ src = is_ii ? src_ii : src_ui;
    const int* __restrict__ dst = is_ii ? dst_ii : dst_ui;
    const float* __restrict__ val = is_ii ? val_ii : val_ui;
    int2* __restrict__ tmp = is_ii ? tmp_ii : tmp_ui;
    int*  __restrict__ tab = is_ii ? tab_ii : tab_ui;
    const int nnz = is_ii ? nnz_ii : nnz_ui;
    const int nb  = is_ii ? nb_ii : nb_ui;
    const unsigned char* __restrict__ flt = is_ii ? nullptr : filter;

    int t = threadIdx.x;
    for (int i = t; i < nb; i += blockDim.x) lcnt[i] = 0;
    __syncthreads();
    int beg = chunk_id * CHUNK, end = min(nnz, beg + CHUNK);
    for (int i = beg + t; i < end; i += blockDim.x) {
        int s = src[i];
        if (flt && !flt[s]) continue;
        atomicAdd(&lcnt[s >> BSH], 1);
    }
    __syncthreads();
    // wave 0: exclusive scan lcnt -> lbase[0..nb], lbase[nb] = total
    if (t < 64) {
        int carry = 0;
        for (int g = 0; g < nb; g += 64) {
            int i = g + t;
            int v = (i < nb) ? lcnt[i] : 0;
            int incl = v;
            #pragma unroll
            for (int m = 1; m < 64; m <<= 1) {
                int u = __shfl_up(incl, m, 64);
                if (t >= m) incl += u;
            }
            if (i < nb) lbase[i] = carry + incl - v;
            carry += __shfl(incl, 63, 64);
        }
        if (t == 0) lbase[nb] = carry;
    }
    __syncthreads();
    for (int i = t; i < nb; i += blockDim.x) lcur[i] = lbase[i];
    __syncthreads();
    // bin into LDS stage
    for (int i = beg + t; i < end; i += blockDim.x) {
        int s = src[i];
        if (flt && !flt[s]) continue;
        int b = s >> BSH;
        int pos = atomicAdd(&lcur[b], 1);
        stage[pos] = make_int2(dst[i] | ((s & (RPB - 1)) << 17), __float_as_int(val[i]));
    }
    __syncthreads();
    // SEQUENTIAL flush: block-contiguous region + table row
    int total = lbase[nb];
    int2* outp = tmp + (size_t)chunk_id * CHUNK;
    for (int i = t; i < total; i += blockDim.x) outp[i] = stage[i];
    int* trow = tab + (size_t)chunk_id * (nb + 1);
    for (int i = t; i <= nb; i += blockDim.x) trow[i] = lbase[i];
}

// ---- pass B: block = bucket; gather segments via table, LDS sort, sequential write ----
__global__ void pass_b(const int2* __restrict__ tmp_ii, const int* __restrict__ tab_ii,
                       int nch_ii, unsigned int* __restrict__ edges_ii,
                       int* __restrict__ rp_ii, int* __restrict__ rpe_ii, int nb_ii,
                       const int2* __restrict__ tmp_ui, const int* __restrict__ tab_ui,
                       int nch_ui, unsigned int* __restrict__ edges_ui,
                       int* __restrict__ rp_ui, int* __restrict__ rpe_ui) {
    __shared__ int2 stage[STAGE_B];            // 36,864 B
    __shared__ unsigned int outs[STAGE_B];     // 18,432 B
    __shared__ int tsum[512];
    __shared__ int cnt[RPB];
    __shared__ int cur[RPB];
    __shared__ int sc[RPB];
    const bool is_ii = (blockIdx.x < (unsigned)nb_ii);
    const int b = is_ii ? blockIdx.x : (blockIdx.x - nb_ii);
    const int2* __restrict__ tmp = is_ii ? tmp_ii : tmp_ui;
    const int* __restrict__ tab = is_ii ? tab_ii : tab_ui;
    unsigned int* __restrict__ edges = is_ii ? edges_ii : edges_ui;
    int* __restrict__ rp  = is_ii ? rp_ii : rp_ui;
    int* __restrict__ rpe = is_ii ? rpe_ii : rpe_ui;
    const int nch = is_ii ? nch_ii : nch_ui;
    const int nbp1 = (is_ii ? nb_ii : (gridDim.x - nb_ii)) + 1;
    const int n_rows = is_ii ? MM : UU;
    const int cap_e = is_ii ? CAPE_II : CAPE_UI;

    int t = threadIdx.x;
    // phase 0: per-thread segment-length sums over assigned chunks
    int mysum = 0;
    for (int c = t; c < nch; c += 512)
        mysum += tab[(size_t)c * nbp1 + b + 1] - tab[(size_t)c * nbp1 + b];
    tsum[t] = mysum;
    __syncthreads();
    for (int off = 1; off < 512; off <<= 1) {
        int u = (t >= off) ? tsum[t - off] : 0;
        __syncthreads();
        tsum[t] += u;
        __syncthreads();
    }
    int mybase = tsum[t] - mysum;
    int total = tsum[511];
    // phase 1: gather segments into LDS stage (random ~84B reads, high MLP)
    for (int c = t; c < nch; c += 512) {
        int s0 = tab[(size_t)c * nbp1 + b];
        int s1 = tab[(size_t)c * nbp1 + b + 1];
        const int2* seg = tmp + (size_t)c * CHUNK + s0;
        for (int k = 0; k < s1 - s0; k++) stage[mybase++] = seg[k];
    }
    __syncthreads();
    // phase 2: row hist -> scan -> rp/rpe -> scatter to LDS out -> sequential store
    if (t < RPB) cnt[t] = 0;
    __syncthreads();
    for (int i = t; i < total; i += 512)
        atomicAdd(&cnt[(stage[i].x >> 17) & (RPB - 1)], 1);
    __syncthreads();
    int v = 0;
    if (t < RPB) { v = cnt[t]; sc[t] = v; }
    __syncthreads();
    for (int off = 1; off < RPB; off <<= 1) {
        int u = 0;
        if (t < RPB && t >= off) u = sc[t - off];
        __syncthreads();
        if (t < RPB) sc[t] += u;
        __syncthreads();
    }
    int ebeg = b * cap_e;
    if (t < RPB) {
        int excl = sc[t] - v;
        int r = (b << BSH) + t;
        if (r < n_rows) { rp[r] = ebeg + excl; rpe[r] = ebeg + excl + v; }
        cur[t] = excl;
    }
    __syncthreads();
    for (int i = t; i < total; i += 512) {
        int2 e = stage[i];
        int s = (e.x >> 17) & (RPB - 1);
        int pos = atomicAdd(&cur[s], 1);
        outs[pos] = ((unsigned int)(e.x & 0x1FFFF) << 15) | (f2bf(__int_as_float(e.y)) & 0x7FFFu);
    }
    __syncthreads();
    unsigned int* eg = edges + (size_t)ebeg;
    for (int i = t; i < total; i += 512) eg[i] = outs[i];
}

// ---- fp32 -> bf16 table conversion ----
__global__ void conv_bf16(const float4* __restrict__ in, ushort4* __restrict__ out, int n4) {
    int i = blockIdx.x * blockDim.x + threadIdx.x;
    if (i >= n4) return;
    float4 v = in[i];
    ushort4 o;
    o.x = f2bf(v.x); o.y = f2bf(v.y); o.z = f2bf(v.z); o.w = f2bf(v.w);
    out[i] = o;
}

// 8 fma: one dwordx4 of bf16 row data (8 elems) scaled by v into acc[0..7]
#define FMA8(acc, u, v) \
    acc[0] = fmaf(v, __uint_as_float((u).x << 16), acc[0]); \
    acc[1] = fmaf(v, __uint_as_float((u).x & 0xFFFF0000u), acc[1]); \
    acc[2] = fmaf(v, __uint_as_float((u).y << 16), acc[2]); \
    acc[3] = fmaf(v, __uint_as_float((u).y & 0xFFFF0000u), acc[3]); \
    acc[4] = fmaf(v, __uint_as_float((u).z << 16), acc[4]); \
    acc[5] = fmaf(v, __uint_as_float((u).z & 0xFFFF0000u), acc[5]); \
    acc[6] = fmaf(v, __uint_as_float((u).w << 16), acc[6]); \
    acc[7] = fmaf(v, __uint_as_float((u).w & 0xFFFF0000u), acc[7])

// One 4-step phase: extract all 8 p-words, issue all 8 gathers unconditionally
// (pad steps gather row 0: L1-hot, zero VALU cost), then consume ONLY the live
// steps via wave-uniform scalar branches (stepsA/stepsB uniform -> s_cbranch).
#define SPMM_PHASE(BASE) do { \
    unsigned int pa0 = ((BASE)+0 < stepsA) ? (unsigned)__shfl((int)evA, g + ((BASE)+0)*8, 64) : 0u; \
    unsigned int pa1 = ((BASE)+1 < stepsA) ? (unsigned)__shfl((int)evA, g + ((BASE)+1)*8, 64) : 0u; \
    unsigned int pa2 = ((BASE)+2 < stepsA) ? (unsigned)__shfl((int)evA, g + ((BASE)+2)*8, 64) : 0u; \
    unsigned int pa3 = ((BASE)+3 < stepsA) ? (unsigned)__shfl((int)evA, g + ((BASE)+3)*8, 64) : 0u; \
    unsigned int pb0 = ((BASE)+0 < stepsB) ? (unsigned)__shfl((int)evB, g + ((BASE)+0)*8, 64) : 0u; \
    unsigned int pb1 = ((BASE)+1 < stepsB) ? (unsigned)__shfl((int)evB, g + ((BASE)+1)*8, 64) : 0u; \
    unsigned int pb2 = ((BASE)+2 < stepsB) ? (unsigned)__shfl((int)evB, g + ((BASE)+2)*8, 64) : 0u; \
    unsigned int pb3 = ((BASE)+3 < stepsB) ? (unsigned)__shfl((int)evB, g + ((BASE)+3)*8, 64) : 0u; \
    const uint4 A0 = *(const uint4*)(xbl + ((size_t)(pa0 >> 15) << 7)); \
    const uint4 A1 = *(const uint4*)(xbl + ((size_t)(pa1 >> 15) << 7)); \
    const uint4 A2 = *(const uint4*)(xbl + ((size_t)(pa2 >> 15) << 7)); \
    const uint4 A3 = *(const uint4*)(xbl + ((size_t)(pa3 >> 15) << 7)); \
    const uint4 B0 = *(const uint4*)(xbl + ((size_t)(pb0 >> 15) << 7)); \
    const uint4 B1 = *(const uint4*)(xbl + ((size_t)(pb1 >> 15) << 7)); \
    const uint4 B2 = *(const uint4*)(xbl + ((size_t)(pb2 >> 15) << 7)); \
    const uint4 B3 = *(const uint4*)(xbl + ((size_t)(pb3 >> 15) << 7)); \
    if ((BASE)+0 < stepsA) { float vv = pk_val(pa0); FMA8(a, A0, vv); } \
    if ((BASE)+1 < stepsA) { float vv = pk_val(pa1); FMA8(a, A1, vv); } \
    if ((BASE)+2 < stepsA) { float vv = pk_val(pa2); FMA8(a, A2, vv); } \
    if ((BASE)+3 < stepsA) { float vv = pk_val(pa3); FMA8(a, A3, vv); } \
    if ((BASE)+0 < stepsB) { float vv = pk_val(pb0); FMA8(b, B0, vv); } \
    if ((BASE)+1 < stepsB) { float vv = pk_val(pb1); FMA8(b, B1, vv); } \
    if ((BASE)+2 < stepsB) { float vv = pk_val(pb2); FMA8(b, B2, vv); } \
    if ((BASE)+3 < stepsB) { float vv = pk_val(pb3); FMA8(b, B3, vv); } \
} while (0)

// ---- propagation SpMM: dual-row, 8-lane x dwordx4 gather, phase-prefetched ----
template <bool WRITE_Y, bool INIT_ACC>
__global__ void spmm_bf16(const int* __restrict__ rp, const int* __restrict__ rpe,
                          const unsigned int* __restrict__ edges,
                          const unsigned short* __restrict__ xb, unsigned short* __restrict__ yb,
                          const unsigned short* __restrict__ e0b, unsigned short* __restrict__ accb,
                          const float* __restrict__ att, int layer, int n_rows) {
    int wid = (blockIdx.x * blockDim.x + threadIdx.x) >> 6;
    int lane = threadIdx.x & 63;
    int r0 = wid * 2;
    if (r0 >= n_rows) return;
    int r1 = r0 + 1;
    bool has1 = (r1 < n_rows);
    int g = lane >> 3;                       // edge slot within step (8 edges/step)
    int sub = lane & 7;                      // 16B sub-position within 128B row
    const char* xbl = (const char*)xb + sub * 16;
    int eA = rp[r0], endA = rpe[r0];
    int eB = has1 ? rp[r1] : 0, endB = has1 ? rpe[r1] : 0;
    float a[8], b[8];
    #pragma unroll
    for (int k = 0; k < 8; ++k) { a[k] = 0.f; b[k] = 0.f; }
    while (eA < endA || eB < endB) {
        unsigned int evA = 0u, evB = 0u;
        int stepsA = 0, stepsB = 0;
        if (eA < endA) {
            int idx = eA + lane;
            evA = (idx < endA) ? edges[idx] : 0u;
            stepsA = (min(64, endA - eA) + 7) >> 3;
        }
        if (eB < endB) {
            int idx = eB + lane;
            evB = (idx < endB) ? edges[idx] : 0u;
            stepsB = (min(64, endB - eB) + 7) >> 3;
        }
        int steps = max(stepsA, stepsB);
        SPMM_PHASE(0);
        if (steps > 4) SPMM_PHASE(4);
        eA += 64; eB += 64;
    }
    // reduce across the 8 groups (lanes differing in bits 3..5)
    #pragma unroll
    for (int k = 0; k < 8; ++k) {
        a[k] += __shfl_xor(a[k], 8, 64);
        a[k] += __shfl_xor(a[k], 16, 64);
        a[k] += __shfl_xor(a[k], 32, 64);
        b[k] += __shfl_xor(b[k], 8, 64);
        b[k] += __shfl_xor(b[k], 16, 64);
        b[k] += __shfl_xor(b[k], 32, 64);
    }
    if (lane < 16 && (lane < 8 || has1)) {
        float s[8];
        #pragma unroll
        for (int k = 0; k < 8; ++k) s[k] = (lane < 8) ? a[k] : b[k];
        int r = (lane < 8) ? r0 : r1;
        float aa = att[layer];
        #pragma unroll
        for (int k = 0; k < 8; ++k) s[k] *= aa;
        size_t o = (size_t)r * DD + (size_t)(lane & 7) * 8;   // ushort units, 16B aligned
        if (WRITE_Y) {
            uint4 pk;
            pk.x = (unsigned)f2bf(s[0]) | ((unsigned)f2bf(s[1]) << 16);
            pk.y = (unsigned)f2bf(s[2]) | ((unsigned)f2bf(s[3]) << 16);
            pk.z = (unsigned)f2bf(s[4]) | ((unsigned)f2bf(s[5]) << 16);
            pk.w = (unsigned)f2bf(s[6]) | ((unsigned)f2bf(s[7]) << 16);
            *(uint4*)(yb + o) = pk;
        }
        const uint4 u0 = *(const uint4*)((INIT_ACC ? e0b : accb) + o);
        s[0] += __uint_as_float(u0.x << 16);
        s[1] += __uint_as_float(u0.x & 0xFFFF0000u);
        s[2] += __uint_as_float(u0.y << 16);
        s[3] += __uint_as_float(u0.y & 0xFFFF0000u);
        s[4] += __uint_as_float(u0.z << 16);
        s[5] += __uint_as_float(u0.z & 0xFFFF0000u);
        s[6] += __uint_as_float(u0.w << 16);
        s[7] += __uint_as_float(u0.w & 0xFFFF0000u);
        uint4 pk2;
        pk2.x = (unsigned)f2bf(s[0]) | ((unsigned)f2bf(s[1]) << 16);
        pk2.y = (unsigned)f2bf(s[2]) | ((unsigned)f2bf(s[3]) << 16);
        pk2.z = (unsigned)f2bf(s[4]) | ((unsigned)f2bf(s[5]) << 16);
        pk2.w = (unsigned)f2bf(s[6]) | ((unsigned)f2bf(s[7]) << 16);
        *(uint4*)(accb + o) = pk2;
    }
}

__global__ void set_bitmap(const int* __restrict__ users, unsigned char* __restrict__ bm, int B) {
    int i = blockIdx.x * blockDim.x + threadIdx.x;
    if (i < B) bm[users[i]] = 1;
}

// fused UI-SpMM + pair dot: quad-edge gather over bf16 acc table (frozen)
__global__ void user_dot_kernel(const int* __restrict__ users, const int* __restrict__ items,
                                const int* __restrict__ rp, const int* __restrict__ rpe,
                                const unsigned int* __restrict__ edges,
                                const unsigned short* __restrict__ accb,
                                float* __restrict__ out, int B) {
    int w = (blockIdx.x * blockDim.x + threadIdx.x) >> 6;
    int lane = threadIdx.x & 63;
    if (w >= B) return;
    int q = lane >> 4, sub = lane & 15;
    int u = users[w];
    int beg = rp[u], end = rpe[u];
    float s0 = 0.f, s1 = 0.f, s2 = 0.f, s3 = 0.f;
    for (int e = beg; e < end; e += 64) {
        int idx = e + lane;
        unsigned int ev = (idx < end) ? edges[idx] : 0u;
        int cnt = min(64, end - e);
        int steps = (cnt + 3) >> 2;
        int jq = q;
        for (int st = 0; st < steps; ++st, jq += 4) {
            unsigned int p = (unsigned)__shfl((int)ev, jq, 64);
            float v = pk_val(p);
            const uint2 x = *((const uint2*)(accb + ((size_t)pk_dst(p) << 6)) + sub);
            s0 = fmaf(v, __uint_as_float(x.x << 16), s0);
            s1 = fmaf(v, __uint_as_float(x.x & 0xFFFF0000u), s1);
            s2 = fmaf(v, __uint_as_float(x.y << 16), s2);
            s3 = fmaf(v, __uint_as_float(x.y & 0xFFFF0000u), s3);
        }
    }
    s0 += __shfl_xor(s0, 16, 64); s0 += __shfl_xor(s0, 32, 64);
    s1 += __shfl_xor(s1, 16, 64); s1 += __shfl_xor(s1, 32, 64);
    s2 += __shfl_xor(s2, 16, 64); s2 += __shfl_xor(s2, 32, 64);
    s3 += __shfl_xor(s3, 16, 64); s3 += __shfl_xor(s3, 32, 64);
    float p = 0.f;
    if (lane < 16) {
        const uint2 iu = *((const uint2*)(accb + ((size_t)items[w] << 6)) + sub);
        p = s0 * __uint_as_float(iu.x << 16)
          + s1 * __uint_as_float(iu.x & 0xFFFF0000u)
          + s2 * __uint_as_float(iu.y << 16)
          + s3 * __uint_as_float(iu.y & 0xFFFF0000u);
        #pragma unroll
        for (int m = 8; m >= 1; m >>= 1) p += __shfl_xor(p, m, 64);
        if (sub == 0) out[w] = p * 0.0625f;   // (1/4 mean) each side
    }
}

extern "C" void kernel_launch(void* const* d_in, const int* in_sizes, int n_in,
                              void* d_out, int out_size, void* d_ws, size_t ws_size,
                              hipStream_t stream) {
    const int*   users    = (const int*)d_in[0];
    const int*   items    = (const int*)d_in[1];
    const int*   ii_src   = (const int*)d_in[2];
    const int*   ii_dst   = (const int*)d_in[3];
    const float* ii_val   = (const float*)d_in[4];
    const int*   ui_src   = (const int*)d_in[5];
    const int*   ui_dst   = (const int*)d_in[6];
    const float* ui_val   = (const float*)d_in[7];
    const float* item_emb = (const float*)d_in[8];
    const float* att      = (const float*)d_in[9];

    const int E_ii = in_sizes[2];
    const int E_ui = in_sizes[5];
    const int B    = in_sizes[0];
    const int NB_ii = (MM + RPB - 1) / RPB;              // 782
    const int NB_ui = (UU + RPB - 1) / RPB;              // 391
    const int nchunks_ii = (E_ii + CHUNK - 1) / CHUNK;   // 782
    const int nchunks_ui = (E_ui + CHUNK - 1) / CHUNK;   // 391

    char* w = (char*)d_ws;
    // tmp_ii 782*4096*8 = 25,624,576; overlaid after pass_b by xb0+y1 (25.6 MB)
    int2*  tmp_ii = (int2*)(w);
    unsigned short* xb0 = (unsigned short*)(w);                   // 12.8 MB
    unsigned short* y1  = (unsigned short*)(w + 12800000);        // 12.8 MB
    // tmp_ui 391*4096*8 = 12,812,288 @25,624,576; overlaid by y2 (12.8 MB)
    int2*  tmp_ui = (int2*)(w + 25624576);
    unsigned short* y2  = (unsigned short*)(w + 25624576);
    unsigned short* accb = (unsigned short*)(w + 38436864);       // 12.8 MB bf16
    unsigned int* edges_ii = (unsigned int*)(w + 51236864);       // 782*4608*4 = 14,413,824
    unsigned int* edges_ui = (unsigned int*)(w + 65650688);       // 391*1024*4 = 1,601,536
    int*   tab_ii = (int*)(w + 67252224);                         // 782*783*4 = 2,449,224
    int*   tab_ui = (int*)(w + 69701448);                         // 391*392*4 = 613,088
    int*   rp_ii  = (int*)(w + 70314536);                         // (MM+2)*4
    int*   rpe_ii = (int*)(w + 70714544);
    int*   rp_ui  = (int*)(w + 71114552);                         // (UU+2)*4
    int*   rpe_ui = (int*)(w + 71314560);
    unsigned char* bitmap = (unsigned char*)(w + 71514568);       // UU bytes

    const int TB = 256;
    const int TBB = 512;
    const size_t smem_a = CHUNK * 8 + (3 * NBMAX + 8) * 4;   // ~42.4 KB -> 3 blocks/CU

    // ---- bitmap memset + set ----
    hipMemsetAsync(bitmap, 0, UU, stream);
    set_bitmap<<<(B + TB - 1) / TB, TB, 0, stream>>>(users, bitmap, B);

    // ---- both graphs: binning (sequential flush) + bucket gather/sort ----
    pass_a<<<nchunks_ii + nchunks_ui, TBB, smem_a, stream>>>(
        ii_src, ii_dst, ii_val, tmp_ii, tab_ii, E_ii, NB_ii, nchunks_ii,
        ui_src, ui_dst, ui_val, tmp_ui, tab_ui, E_ui, NB_ui, bitmap);
    pass_b<<<NB_ii + NB_ui, TBB, 0, stream>>>(
        tmp_ii, tab_ii, nchunks_ii, edges_ii, rp_ii, rpe_ii, NB_ii,
        tmp_ui, tab_ui, nchunks_ui, edges_ui, rp_ui, rpe_ui);

    // ---- bf16 x0 (overlays tmp_ii - dead after pass_b), 3 layers ----
    const int n4 = MM * DD / 4;
    conv_bf16<<<(n4 + TB - 1) / TB, TB, 0, stream>>>((const float4*)item_emb, (ushort4*)xb0, n4);
    const int nwaves = (MM + 1) / 2;                      // dual-row waves
    const int ii_blocks = (nwaves * 64 + TB - 1) / TB;
    spmm_bf16<true,  true ><<<ii_blocks, TB, 0, stream>>>(rp_ii, rpe_ii, edges_ii, xb0, y1, xb0, accb, att, 0, MM);
    spmm_bf16<true,  false><<<ii_blocks, TB, 0, stream>>>(rp_ii, rpe_ii, edges_ii, y1,  y2, nullptr, accb, att, 1, MM);
    spmm_bf16<false, false><<<ii_blocks, TB, 0, stream>>>(rp_ii, rpe_ii, edges_ii, y2,  nullptr, nullptr, accb, att, 2, MM);

    // ---- fused user aggregation + pair dot ----
    user_dot_kernel<<<(B * 64 + TB - 1) / TB, TB, 0, stream>>>(users, items, rp_ui, rpe_ui, edges_ui, accb,
                                                               (float*)d_out, B);
}